// Round 8
// baseline (159.711 us; speedup 1.0000x reference)
//
// Round 7: self-repairing hybrid. Grid build + grid query write outputs;
// frs_check brute-verifies OUTPUT ROWS directly (positions, values, padding,
// counts) and repairs mismatched rows in place -> passes in every outcome.
// Next-round bisect: strip checker. (Rounds 4-7 were broker timeouts.)
#include <hip/hip_runtime.h>
#include <hip/hip_bf16.h>

#define NPTS 8192
#define NQRY 8192
#define KMAX 128
#define G 10
#define NCELL 1000
#define RANGE_EPS 1e-5f

// ---- workspace layout (bytes from d_ws) ----
#define WS_COUNTS 0        // counts[8192] int (offset 0 proven writable in r1)
#define WS_SORTED 32768    // sorted float4[8192] (x,y,z, idx-bits)
#define WS_CSTART 163840   // cell_start[1001] int
#define WS_NEED 167872

__device__ __forceinline__ int cell_clamp(float v) {
  int c = (int)floorf(v * 10.0f);
  return c < 0 ? 0 : (c > G - 1 ? G - 1 : c);
}

// Single-block grid build: LDS histogram -> LDS scan -> scatter.
__global__ __launch_bounds__(1024) void frs_build(
    const float* __restrict__ pts, float4* __restrict__ sorted,
    int* __restrict__ cell_start) {
  __shared__ int s_cnt[NCELL];
  __shared__ int s_tmp[16];
  const int t = threadIdx.x;
  if (t < NCELL) s_cnt[t] = 0;
  __syncthreads();

  float px[8], py[8], pz[8];
  int pc[8];
#pragma unroll
  for (int k = 0; k < 8; ++k) {
    const int pid = k * 1024 + t;
    px[k] = pts[pid * 3 + 0];
    py[k] = pts[pid * 3 + 1];
    pz[k] = pts[pid * 3 + 2];
    pc[k] = (cell_clamp(px[k]) * G + cell_clamp(py[k])) * G + cell_clamp(pz[k]);
    atomicAdd(&s_cnt[pc[k]], 1);
  }
  __syncthreads();

  const int lane = t & 63, wid = t >> 6;
  const int v = (t < NCELL) ? s_cnt[t] : 0;
  int incl = v;
#pragma unroll
  for (int off = 1; off < 64; off <<= 1) {
    const int u = __shfl_up(incl, off, 64);
    if (lane >= off) incl += u;
  }
  if (lane == 63) s_tmp[wid] = incl;
  __syncthreads();
  if (t == 0) {
    int run = 0;
    for (int i = 0; i < 16; ++i) {
      const int x = s_tmp[i];
      s_tmp[i] = run;
      run += x;
    }
  }
  __syncthreads();
  const int excl = s_tmp[wid] + (incl - v);
  if (t < NCELL) {
    cell_start[t] = excl;
    s_cnt[t] = excl;
  }
  if (t == NCELL - 1) cell_start[NCELL] = excl + v;
  __syncthreads();

#pragma unroll
  for (int k = 0; k < 8; ++k) {
    const int pos = atomicAdd(&s_cnt[pc[k]], 1);
    sorted[pos] = make_float4(px[k], py[k], pz[k], __int_as_float(k * 1024 + t));
  }
}

// Grid query: collect hits into LDS, rank-by-count reorder, write outputs.
__global__ __launch_bounds__(256) void frs_query_g(
    const float4* __restrict__ sorted, const int* __restrict__ cstart,
    const float* __restrict__ qrs, const float* __restrict__ rad,
    float* __restrict__ out_idx, float* __restrict__ out_dist,
    int* __restrict__ counts) {
  __shared__ int hidx[4][KMAX];
  __shared__ float hd2[4][KMAX];

  const int lane = threadIdx.x & 63;
  const int wid = threadIdx.x >> 6;
  const int q = blockIdx.x * 4 + wid;

  const float qx = qrs[q * 3 + 0];
  const float qy = qrs[q * 3 + 1];
  const float qz = qrs[q * 3 + 2];
  const float r = rad[0];
  const float r2 = __fmul_rn(r, r);
  const float qq = __fadd_rn(
      __fadd_rn(__fmul_rn(qx, qx), __fmul_rn(qy, qy)), __fmul_rn(qz, qz));

  const float rm = r + RANGE_EPS;
  const int x0 = cell_clamp(qx - rm), x1 = cell_clamp(qx + rm);
  const int y0 = cell_clamp(qy - rm), y1 = cell_clamp(qy + rm);
  const int z0 = cell_clamp(qz - rm), z1 = cell_clamp(qz + rm);

  const unsigned long long lt = (1ull << lane) - 1ull;
  int cnt = 0;

  for (int cx = x0; cx <= x1; ++cx) {
    for (int cy = y0; cy <= y1; ++cy) {
      const int rb = (cx * G + cy) * G;
      const int s = cstart[rb + z0];
      const int e = cstart[rb + z1 + 1];
      for (int jb = s; jb < e; jb += 64) {
        const int j = jb + lane;
        const bool act = j < e;
        const float4 p = sorted[act ? j : s];
        const float pp = __fadd_rn(
            __fadd_rn(__fmul_rn(p.x, p.x), __fmul_rn(p.y, p.y)),
            __fmul_rn(p.z, p.z));
        const float dot = __fadd_rn(
            __fadd_rn(__fmul_rn(qx, p.x), __fmul_rn(qy, p.y)),
            __fmul_rn(qz, p.z));
        float d2 = __fsub_rn(__fadd_rn(qq, pp), __fmul_rn(2.0f, dot));
        d2 = fmaxf(d2, 0.0f);
        const bool hit = act && (d2 <= r2);
        const unsigned long long m = __ballot(hit);
        if (hit) {
          const int pos = cnt + __popcll(m & lt);
          if (pos < KMAX) {
            hidx[wid][pos] = __float_as_int(p.w);
            hd2[wid][pos] = d2;
          }
        }
        cnt += __popcll(m);
      }
    }
  }

  const int cc = cnt < KMAX ? cnt : KMAX;
  float* const oi = out_idx + (size_t)q * KMAX;
  float* const od = out_dist + (size_t)q * KMAX;

  // rank-by-counting reorder (ranks are a permutation of 0..cc-1)
  const int i0 = lane, i1 = lane + 64;
  const int k0 = (i0 < cc) ? hidx[wid][i0] : 0;
  const float v0 = (i0 < cc) ? hd2[wid][i0] : 0.0f;
  const int k1 = (i1 < cc) ? hidx[wid][i1] : 0;
  const float v1 = (i1 < cc) ? hd2[wid][i1] : 0.0f;
  int r0 = 0, r1 = 0;
  for (int s = 0; s < cc; ++s) {
    const int ks = hidx[wid][s];
    r0 += (ks < k0);
    r1 += (ks < k1);
  }
  if (i0 < cc) {
    oi[r0] = (float)k0;
    od[r0] = v0;
  } else {
    oi[i0] = -1.0f;
    od[i0] = 0.0f;
  }
  if (i1 < cc) {
    oi[r1] = (float)k1;
    od[r1] = v1;
  } else {
    oi[i1] = -1.0f;
    od[i1] = 0.0f;
  }
  if (lane == 0) counts[q] = cnt;
}

// Brute-force OUTPUT verifier + in-place repair. 8 waves = 8 queries/block.
// Verifies positions, values (bit-exact: identical fp chain), padding, count.
__global__ __launch_bounds__(512) void frs_check(
    const float* __restrict__ pts, const float* __restrict__ qrs,
    const float* __restrict__ rad, float* __restrict__ out_idx,
    float* __restrict__ out_dist, int* __restrict__ counts) {
  __shared__ float4 sp[2048];
  __shared__ int s_flag;

  const int lane = threadIdx.x & 63;
  const int wid = threadIdx.x >> 6;  // 0..7
  const int q = blockIdx.x * 8 + wid;
  if (threadIdx.x == 0) s_flag = 0;

  const float qx = qrs[q * 3 + 0];
  const float qy = qrs[q * 3 + 1];
  const float qz = qrs[q * 3 + 2];
  const float r = rad[0];
  const float r2 = __fmul_rn(r, r);
  const float qq = __fadd_rn(
      __fadd_rn(__fmul_rn(qx, qx), __fmul_rn(qy, qy)), __fmul_rn(qz, qz));

  const unsigned long long lt = (1ull << lane) - 1ull;
  float* const oi = out_idx + (size_t)q * KMAX;
  float* const od = out_dist + (size_t)q * KMAX;

  int cnt = 0;
  bool ok = true;

  for (int t0 = 0; t0 < NPTS; t0 += 2048) {
    __syncthreads();
    for (int i = threadIdx.x; i < 2048; i += 512) {
      const int pi = t0 + i;
      const float x = pts[pi * 3 + 0];
      const float y = pts[pi * 3 + 1];
      const float z = pts[pi * 3 + 2];
      const float pp = __fadd_rn(
          __fadd_rn(__fmul_rn(x, x), __fmul_rn(y, y)), __fmul_rn(z, z));
      sp[i] = make_float4(x, y, z, pp);
    }
    __syncthreads();

    for (int j = lane; j < 2048; j += 64) {
      const float4 p = sp[j];
      const float dot = __fadd_rn(
          __fadd_rn(__fmul_rn(qx, p.x), __fmul_rn(qy, p.y)),
          __fmul_rn(qz, p.z));
      float d2 = __fsub_rn(__fadd_rn(qq, p.w), __fmul_rn(2.0f, dot));
      d2 = fmaxf(d2, 0.0f);
      const bool hit = d2 <= r2;
      const unsigned long long m = __ballot(hit);
      if (hit) {
        const int pos = cnt + __popcll(m & lt);
        if (pos < KMAX) {
          ok = ok && (oi[pos] == (float)(t0 + j)) && (od[pos] == d2);
        }
      }
      cnt += __popcll(m);
    }
  }
  // padding + count verification
  const int cc = cnt < KMAX ? cnt : KMAX;
  for (int s = cc + lane; s < KMAX; s += 64) {
    ok = ok && (oi[s] == -1.0f) && (od[s] == 0.0f);
  }
  ok = ok && (counts[q] == cnt);

  const bool repair = !__all(ok);  // wave-uniform verdict
  if (lane == 0 && repair) atomicOr(&s_flag, 1);
  __syncthreads();

  if (s_flag) {  // block-uniform: someone needs repair -> all re-stage tiles
    int rcnt = 0;
    for (int t0 = 0; t0 < NPTS; t0 += 2048) {
      __syncthreads();
      for (int i = threadIdx.x; i < 2048; i += 512) {
        const int pi = t0 + i;
        const float x = pts[pi * 3 + 0];
        const float y = pts[pi * 3 + 1];
        const float z = pts[pi * 3 + 2];
        const float pp = __fadd_rn(
            __fadd_rn(__fmul_rn(x, x), __fmul_rn(y, y)), __fmul_rn(z, z));
        sp[i] = make_float4(x, y, z, pp);
      }
      __syncthreads();
      if (repair) {
        for (int j = lane; j < 2048; j += 64) {
          const float4 p = sp[j];
          const float dot = __fadd_rn(
              __fadd_rn(__fmul_rn(qx, p.x), __fmul_rn(qy, p.y)),
              __fmul_rn(qz, p.z));
          float d2 = __fsub_rn(__fadd_rn(qq, p.w), __fmul_rn(2.0f, dot));
          d2 = fmaxf(d2, 0.0f);
          const bool hit = d2 <= r2;
          const unsigned long long m = __ballot(hit);
          if (hit) {
            const int pos = rcnt + __popcll(m & lt);
            if (pos < KMAX) {
              oi[pos] = (float)(t0 + j);
              od[pos] = d2;
            }
          }
          rcnt += __popcll(m);
        }
      }
    }
    if (repair) {
      for (int s = rcnt + lane; s < KMAX; s += 64) {
        oi[s] = -1.0f;
        od[s] = 0.0f;
      }
      if (lane == 0) counts[q] = rcnt;
    }
  }
}

// Round-1 proven brute-force fallback (needs only counts[] in ws).
__global__ __launch_bounds__(256) void frs_brute(
    const float* __restrict__ pts, const float* __restrict__ qrs,
    const float* __restrict__ rad, float* __restrict__ out_idx,
    float* __restrict__ out_dist, int* __restrict__ counts) {
  __shared__ float4 sp[2048];

  const int lane = threadIdx.x & 63;
  const int wid = threadIdx.x >> 6;
  const int q = blockIdx.x * 4 + wid;

  const float q0 = qrs[q * 3 + 0];
  const float q1 = qrs[q * 3 + 1];
  const float q2 = qrs[q * 3 + 2];
  const float r = rad[0];
  const float r2 = __fmul_rn(r, r);
  const float qq = __fadd_rn(
      __fadd_rn(__fmul_rn(q0, q0), __fmul_rn(q1, q1)), __fmul_rn(q2, q2));

  const unsigned long long lt = (1ull << lane) - 1ull;
  int count = 0;

  float* const oi = out_idx + (size_t)q * KMAX;
  float* const od = out_dist + (size_t)q * KMAX;

  for (int t0 = 0; t0 < NPTS; t0 += 2048) {
    __syncthreads();
    for (int i = threadIdx.x; i < 2048; i += 256) {
      const int pi = t0 + i;
      const float x = pts[pi * 3 + 0];
      const float y = pts[pi * 3 + 1];
      const float z = pts[pi * 3 + 2];
      const float pp = __fadd_rn(
          __fadd_rn(__fmul_rn(x, x), __fmul_rn(y, y)), __fmul_rn(z, z));
      sp[i] = make_float4(x, y, z, pp);
    }
    __syncthreads();

    for (int j = lane; j < 2048; j += 64) {
      const float4 p = sp[j];
      const float dot = __fadd_rn(
          __fadd_rn(__fmul_rn(q0, p.x), __fmul_rn(q1, p.y)),
          __fmul_rn(q2, p.z));
      float d2 = __fsub_rn(__fadd_rn(qq, p.w), __fmul_rn(2.0f, dot));
      d2 = fmaxf(d2, 0.0f);
      const bool hit = d2 <= r2;
      const unsigned long long m = __ballot(hit);
      if (hit) {
        const int pos = count + __popcll(m & lt);
        if (pos < KMAX) {
          oi[pos] = (float)(t0 + j);
          od[pos] = d2;
        }
      }
      count += __popcll(m);
    }
  }

  for (int s = count + lane; s < KMAX; s += 64) {
    oi[s] = -1.0f;
    od[s] = 0.0f;
  }
  if (lane == 0) counts[q] = count;
}

// Single-block exclusive prefix sum of 8192 counts -> row_splits[8193] (float).
__global__ __launch_bounds__(1024) void frs_scan_kernel(
    const int* __restrict__ counts, float* __restrict__ row_splits) {
  const int t = threadIdx.x;
  const int base = t * 8;
  int c[8];
  int s = 0;
#pragma unroll
  for (int i = 0; i < 8; i++) {
    c[i] = counts[base + i];
    s += c[i];
  }
  const int lane = t & 63;
  const int wid = t >> 6;
  int incl = s;
#pragma unroll
  for (int off = 1; off < 64; off <<= 1) {
    const int v = __shfl_up(incl, off, 64);
    if (lane >= off) incl += v;
  }
  __shared__ int wpart[16];
  if (lane == 63) wpart[wid] = incl;
  __syncthreads();
  if (t == 0) {
    int run = 0;
    for (int i = 0; i < 16; i++) {
      const int v = wpart[i];
      wpart[i] = run;
      run += v;
    }
  }
  __syncthreads();
  const int excl = wpart[wid] + (incl - s);
  int run = excl;
#pragma unroll
  for (int i = 0; i < 8; i++) {
    row_splits[base + i] = (float)run;
    run += c[i];
  }
  if (t == 1023) row_splits[NQRY] = (float)run;
}

extern "C" void kernel_launch(void* const* d_in, const int* in_sizes, int n_in,
                              void* d_out, int out_size, void* d_ws, size_t ws_size,
                              hipStream_t stream) {
  const float* pts = (const float*)d_in[0];
  const float* qrs = (const float*)d_in[1];
  const float* rad = (const float*)d_in[2];

  float* out = (float*)d_out;
  float* out_idx = out;
  float* row_splits = out + (size_t)NQRY * KMAX;
  float* out_dist = row_splits + (NQRY + 1);

  char* ws = (char*)d_ws;
  int* counts = (int*)(ws + WS_COUNTS);
  float4* sorted = (float4*)(ws + WS_SORTED);
  int* cell_start = (int*)(ws + WS_CSTART);

  if (ws_size >= (size_t)WS_NEED) {
    frs_build<<<1, 1024, 0, stream>>>(pts, sorted, cell_start);
    frs_query_g<<<NQRY / 4, 256, 0, stream>>>(sorted, cell_start, qrs, rad,
                                              out_idx, out_dist, counts);
    frs_check<<<NQRY / 8, 512, 0, stream>>>(pts, qrs, rad, out_idx, out_dist,
                                            counts);
  } else {
    frs_brute<<<NQRY / 4, 256, 0, stream>>>(pts, qrs, rad, out_idx, out_dist,
                                            counts);
  }
  frs_scan_kernel<<<1, 1024, 0, stream>>>(counts, row_splits);
}

// Round 11
// 95.792 us; speedup vs baseline: 1.6673x; 1.6673x over previous
//
// Round 11 = round 9 retry #2 (rounds 9-10 were infra failures: broker
// timeout, then container failure; no kernel signal). Optimized brute force:
// 8 queries/block, coalesced float4 staging, p^2 pre-pass in LDS, 100%
// occupancy. The d2 chain + ballot-compact output logic is bit-identical to
// the twice-proven round-1 kernel.
#include <hip/hip_runtime.h>
#include <hip/hip_bf16.h>

#define NPTS 8192
#define NQRY 8192
#define KMAX 128
#define TILE 2048

// ws: counts[8192] int at offset 0 (proven writable in rounds 1/8)

__global__ __launch_bounds__(512) void frs_brute8(
    const float* __restrict__ pts, const float* __restrict__ qrs,
    const float* __restrict__ rad, float* __restrict__ out_idx,
    float* __restrict__ out_dist, int* __restrict__ counts) {
  __shared__ float sraw[TILE * 3];  // 24 KB raw xyz
  __shared__ float spp[TILE];       // 8 KB  |p|^2

  const int tid = threadIdx.x;
  const int lane = tid & 63;
  const int wid = tid >> 6;  // 0..7
  const int q = blockIdx.x * 8 + wid;

  const float qx = qrs[q * 3 + 0];
  const float qy = qrs[q * 3 + 1];
  const float qz = qrs[q * 3 + 2];
  const float r = rad[0];
  const float r2 = __fmul_rn(r, r);
  // qq = (qx*qx + qy*qy) + qz*qz  — np association, no FMA contraction
  const float qq = __fadd_rn(
      __fadd_rn(__fmul_rn(qx, qx), __fmul_rn(qy, qy)), __fmul_rn(qz, qz));

  const unsigned long long lt = (1ull << lane) - 1ull;
  int cnt = 0;
  float* const oi = out_idx + (size_t)q * KMAX;
  float* const od = out_dist + (size_t)q * KMAX;

  for (int t0 = 0; t0 < NPTS; t0 += TILE) {
    __syncthreads();  // previous tile fully consumed
    // coalesced staging: TILE*3 floats = TILE*3/4 float4s (16B-aligned: t0*12B)
    {
      const float4* __restrict__ src = (const float4*)(pts + t0 * 3);
      float4* dst = (float4*)sraw;
#pragma unroll
      for (int i = tid; i < TILE * 3 / 4; i += 512) dst[i] = src[i];
    }
    __syncthreads();
    // p^2 pre-pass (amortized over 8 waves): pp = (x*x + y*y) + z*z
    for (int p = tid; p < TILE; p += 512) {
      const float x = sraw[3 * p + 0];
      const float y = sraw[3 * p + 1];
      const float z = sraw[3 * p + 2];
      spp[p] = __fadd_rn(
          __fadd_rn(__fmul_rn(x, x), __fmul_rn(y, y)), __fmul_rn(z, z));
    }
    __syncthreads();
    // per-wave scan: 32 iterations of 64 points
    for (int j = lane; j < TILE; j += 64) {
      const float x = sraw[3 * j + 0];  // stride-3: conflict-free (3 coprime 32)
      const float y = sraw[3 * j + 1];
      const float z = sraw[3 * j + 2];
      const float pp = spp[j];
      const float dot = __fadd_rn(
          __fadd_rn(__fmul_rn(qx, x), __fmul_rn(qy, y)), __fmul_rn(qz, z));
      float d2 = __fsub_rn(__fadd_rn(qq, pp), __fmul_rn(2.0f, dot));
      d2 = fmaxf(d2, 0.0f);
      const bool hit = d2 <= r2;
      const unsigned long long m = __ballot(hit);
      if (hit) {
        const int pos = cnt + __popcll(m & lt);
        if (pos < KMAX) {
          oi[pos] = (float)(t0 + j);
          od[pos] = d2;
        }
      }
      cnt += __popcll(m);
    }
  }

  // padding: idx = -1, dist = 0
  for (int s = cnt + lane; s < KMAX; s += 64) {
    oi[s] = -1.0f;
    od[s] = 0.0f;
  }
  if (lane == 0) counts[q] = cnt;
}

// Single-block exclusive prefix sum of 8192 counts -> row_splits[8193] (float).
__global__ __launch_bounds__(1024) void frs_scan_kernel(
    const int* __restrict__ counts, float* __restrict__ row_splits) {
  const int t = threadIdx.x;
  const int base = t * 8;
  int c[8];
  int s = 0;
#pragma unroll
  for (int i = 0; i < 8; i++) {
    c[i] = counts[base + i];
    s += c[i];
  }
  const int lane = t & 63;
  const int wid = t >> 6;
  int incl = s;
#pragma unroll
  for (int off = 1; off < 64; off <<= 1) {
    const int v = __shfl_up(incl, off, 64);
    if (lane >= off) incl += v;
  }
  __shared__ int wpart[16];
  if (lane == 63) wpart[wid] = incl;
  __syncthreads();
  if (t == 0) {
    int run = 0;
    for (int i = 0; i < 16; i++) {
      const int v = wpart[i];
      wpart[i] = run;
      run += v;
    }
  }
  __syncthreads();
  const int excl = wpart[wid] + (incl - s);
  int run = excl;
#pragma unroll
  for (int i = 0; i < 8; i++) {
    row_splits[base + i] = (float)run;
    run += c[i];
  }
  if (t == 1023) row_splits[NQRY] = (float)run;
}

extern "C" void kernel_launch(void* const* d_in, const int* in_sizes, int n_in,
                              void* d_out, int out_size, void* d_ws, size_t ws_size,
                              hipStream_t stream) {
  const float* pts = (const float*)d_in[0];  // [N,3]
  const float* qrs = (const float*)d_in[1];  // [Q,3]
  const float* rad = (const float*)d_in[2];  // scalar

  float* out = (float*)d_out;
  float* out_idx = out;                           // [Q,K]
  float* row_splits = out + (size_t)NQRY * KMAX;  // [Q+1]
  float* out_dist = row_splits + (NQRY + 1);      // [Q,K]

  int* counts = (int*)d_ws;  // 8192 ints

  frs_brute8<<<NQRY / 8, 512, 0, stream>>>(pts, qrs, rad, out_idx, out_dist,
                                           counts);
  frs_scan_kernel<<<1, 1024, 0, stream>>>(counts, row_splits);
}

// Round 12
// 91.955 us; speedup vs baseline: 1.7368x; 1.0417x over previous
//
// Round 12: instruction-count-optimized brute. r11 decomposition: harness
// d_ws re-poison fill ≈ 40us is fixed; frs_brute8 ≈ 42us because 4x ds_read_b32
// + dual addr chains ADDED VALU work vs r1's single ds_read_b128 (kernel is
// VALU-issue bound: 8192 waves x 128 iters x N_instr). v2: float4 LDS (1 b128/
// point), unroll-4 (shared base addr + ILP), skip compact when ballot==0
// (~75% of iters). d2 chain / ballot order / outputs bit-identical to proven.
#include <hip/hip_runtime.h>
#include <hip/hip_bf16.h>

#define NPTS 8192
#define NQRY 8192
#define KMAX 128
#define TILE 2048

// ws: counts[8192] int at offset 0 (proven writable in rounds 1/8/11)

__global__ __launch_bounds__(512) void frs_v2(
    const float* __restrict__ pts, const float* __restrict__ qrs,
    const float* __restrict__ rad, float* __restrict__ out_idx,
    float* __restrict__ out_dist, int* __restrict__ counts) {
  __shared__ float4 sp[TILE];  // 32 KB: x, y, z, |p|^2  -> 4 blocks/CU

  const int tid = threadIdx.x;
  const int lane = tid & 63;
  const int wid = tid >> 6;  // 0..7
  const int q = blockIdx.x * 8 + wid;

  const float qx = qrs[q * 3 + 0];
  const float qy = qrs[q * 3 + 1];
  const float qz = qrs[q * 3 + 2];
  const float r = rad[0];
  const float r2 = __fmul_rn(r, r);
  // qq = (qx*qx + qy*qy) + qz*qz  — np association, no FMA contraction
  const float qq = __fadd_rn(
      __fadd_rn(__fmul_rn(qx, qx), __fmul_rn(qy, qy)), __fmul_rn(qz, qz));

  const unsigned long long lt = (1ull << lane) - 1ull;
  int cnt = 0;
  float* const oi = out_idx + (size_t)q * KMAX;
  float* const od = out_dist + (size_t)q * KMAX;

  for (int t0 = 0; t0 < NPTS; t0 += TILE) {
    __syncthreads();  // previous tile fully consumed
    // staging: 4 points/thread; scalar stride-3 loads stay in cache lines
    for (int p = tid; p < TILE; p += 512) {
      const int pi = t0 + p;
      const float x = pts[pi * 3 + 0];
      const float y = pts[pi * 3 + 1];
      const float z = pts[pi * 3 + 2];
      const float pp = __fadd_rn(
          __fadd_rn(__fmul_rn(x, x), __fmul_rn(y, y)), __fmul_rn(z, z));
      sp[p] = make_float4(x, y, z, pp);
    }
    __syncthreads();
    // per-wave scan, unroll 4: one ds_read_b128 base + offset imms, 4-wide ILP
#pragma unroll 4
    for (int j = lane; j < TILE; j += 64) {
      const float4 p = sp[j];
      const float dot = __fadd_rn(
          __fadd_rn(__fmul_rn(qx, p.x), __fmul_rn(qy, p.y)),
          __fmul_rn(qz, p.z));
      float d2 = __fsub_rn(__fadd_rn(qq, p.w), __fmul_rn(2.0f, dot));
      d2 = fmaxf(d2, 0.0f);
      const bool hit = d2 <= r2;
      const unsigned long long m = __ballot(hit);
      if (m) {  // skip compaction machinery when the whole wave missed
        if (hit) {
          const int pos = cnt + __popcll(m & lt);
          if (pos < KMAX) {
            oi[pos] = (float)(t0 + j);
            od[pos] = d2;
          }
        }
        cnt += __popcll(m);
      }
    }
  }

  // padding: idx = -1, dist = 0
  for (int s = cnt + lane; s < KMAX; s += 64) {
    oi[s] = -1.0f;
    od[s] = 0.0f;
  }
  if (lane == 0) counts[q] = cnt;
}

// Single-block exclusive prefix sum of 8192 counts -> row_splits[8193] (float).
__global__ __launch_bounds__(1024) void frs_scan_kernel(
    const int* __restrict__ counts, float* __restrict__ row_splits) {
  const int t = threadIdx.x;
  const int base = t * 8;
  int c[8];
  int s = 0;
#pragma unroll
  for (int i = 0; i < 8; i++) {
    c[i] = counts[base + i];
    s += c[i];
  }
  const int lane = t & 63;
  const int wid = t >> 6;
  int incl = s;
#pragma unroll
  for (int off = 1; off < 64; off <<= 1) {
    const int v = __shfl_up(incl, off, 64);
    if (lane >= off) incl += v;
  }
  __shared__ int wpart[16];
  if (lane == 63) wpart[wid] = incl;
  __syncthreads();
  if (t == 0) {
    int run = 0;
    for (int i = 0; i < 16; i++) {
      const int v = wpart[i];
      wpart[i] = run;
      run += v;
    }
  }
  __syncthreads();
  const int excl = wpart[wid] + (incl - s);
  int run = excl;
#pragma unroll
  for (int i = 0; i < 8; i++) {
    row_splits[base + i] = (float)run;
    run += c[i];
  }
  if (t == 1023) row_splits[NQRY] = (float)run;
}

extern "C" void kernel_launch(void* const* d_in, const int* in_sizes, int n_in,
                              void* d_out, int out_size, void* d_ws, size_t ws_size,
                              hipStream_t stream) {
  const float* pts = (const float*)d_in[0];  // [N,3]
  const float* qrs = (const float*)d_in[1];  // [Q,3]
  const float* rad = (const float*)d_in[2];  // scalar

  float* out = (float*)d_out;
  float* out_idx = out;                           // [Q,K]
  float* row_splits = out + (size_t)NQRY * KMAX;  // [Q+1]
  float* out_dist = row_splits + (NQRY + 1);      // [Q,K]

  int* counts = (int*)d_ws;  // 8192 ints

  frs_v2<<<NQRY / 8, 512, 0, stream>>>(pts, qrs, rad, out_idx, out_dist,
                                       counts);
  frs_scan_kernel<<<1, 1024, 0, stream>>>(counts, row_splits);
}

// Round 13
// 91.658 us; speedup vs baseline: 1.7425x; 1.0032x over previous
//
// Round 13: 2 queries per wave. r12 analysis: harness d_ws fill (268MB,
// ~40.7us) + graph gaps (~10us) are fixed; frs_v2 ≈ 35-38us with empirical
// ~30 issued VALU/pair (r1-calibrated issue model). The LDS read + addressing
// + loop overhead is per-POINT: amortize it over 2 queries/wave (query coords
// wave-uniform -> SGPRs). Halves LDS traffic, per-pair instr ~14. Per-query
// ballot-compact output logic bit-identical to the proven brute path.
#include <hip/hip_runtime.h>
#include <hip/hip_bf16.h>

#define NPTS 8192
#define NQRY 8192
#define KMAX 128
#define TILE 2048

// ws: counts[8192] int at offset 0 (proven writable in rounds 1/8/11/12)

__global__ __launch_bounds__(512) void frs_v3(
    const float* __restrict__ pts, const float* __restrict__ qrs,
    const float* __restrict__ rad, float* __restrict__ out_idx,
    float* __restrict__ out_dist, int* __restrict__ counts) {
  __shared__ float4 sp[TILE];  // 32 KB: x, y, z, |p|^2 -> 4 blocks/CU

  const int tid = threadIdx.x;
  const int lane = tid & 63;
  const int wid = tid >> 6;  // 0..7
  const int qA = blockIdx.x * 16 + wid * 2;  // 512 blocks x 8 waves x 2 queries
  const int qB = qA + 1;

  const float ax = qrs[qA * 3 + 0], ay = qrs[qA * 3 + 1], az = qrs[qA * 3 + 2];
  const float bx = qrs[qB * 3 + 0], by = qrs[qB * 3 + 1], bz = qrs[qB * 3 + 2];
  const float r = rad[0];
  const float r2 = __fmul_rn(r, r);
  // qq = (qx*qx + qy*qy) + qz*qz — np association, no FMA contraction
  const float qqA = __fadd_rn(
      __fadd_rn(__fmul_rn(ax, ax), __fmul_rn(ay, ay)), __fmul_rn(az, az));
  const float qqB = __fadd_rn(
      __fadd_rn(__fmul_rn(bx, bx), __fmul_rn(by, by)), __fmul_rn(bz, bz));

  const unsigned long long lt = (1ull << lane) - 1ull;
  int cA = 0, cB = 0;
  float* const oiA = out_idx + (size_t)qA * KMAX;
  float* const odA = out_dist + (size_t)qA * KMAX;
  float* const oiB = out_idx + (size_t)qB * KMAX;
  float* const odB = out_dist + (size_t)qB * KMAX;

  for (int t0 = 0; t0 < NPTS; t0 += TILE) {
    __syncthreads();  // previous tile fully consumed
    for (int p = tid; p < TILE; p += 512) {
      const int pi = t0 + p;
      const float x = pts[pi * 3 + 0];
      const float y = pts[pi * 3 + 1];
      const float z = pts[pi * 3 + 2];
      const float pp = __fadd_rn(
          __fadd_rn(__fmul_rn(x, x), __fmul_rn(y, y)), __fmul_rn(z, z));
      sp[p] = make_float4(x, y, z, pp);
    }
    __syncthreads();

#pragma unroll 4
    for (int j = lane; j < TILE; j += 64) {
      const float4 p = sp[j];  // one b128 read feeds both queries
      // query A
      const float dotA = __fadd_rn(
          __fadd_rn(__fmul_rn(ax, p.x), __fmul_rn(ay, p.y)),
          __fmul_rn(az, p.z));
      float dA = __fsub_rn(__fadd_rn(qqA, p.w), __fmul_rn(2.0f, dotA));
      dA = fmaxf(dA, 0.0f);
      // query B
      const float dotB = __fadd_rn(
          __fadd_rn(__fmul_rn(bx, p.x), __fmul_rn(by, p.y)),
          __fmul_rn(bz, p.z));
      float dB = __fsub_rn(__fadd_rn(qqB, p.w), __fmul_rn(2.0f, dotB));
      dB = fmaxf(dB, 0.0f);

      const bool hitA = dA <= r2;
      const unsigned long long mA = __ballot(hitA);
      if (mA) {
        if (hitA) {
          const int pos = cA + __popcll(mA & lt);
          if (pos < KMAX) {
            oiA[pos] = (float)(t0 + j);
            odA[pos] = dA;
          }
        }
        cA += __popcll(mA);
      }
      const bool hitB = dB <= r2;
      const unsigned long long mB = __ballot(hitB);
      if (mB) {
        if (hitB) {
          const int pos = cB + __popcll(mB & lt);
          if (pos < KMAX) {
            oiB[pos] = (float)(t0 + j);
            odB[pos] = dB;
          }
        }
        cB += __popcll(mB);
      }
    }
  }

  // padding: idx = -1, dist = 0
  for (int s = cA + lane; s < KMAX; s += 64) {
    oiA[s] = -1.0f;
    odA[s] = 0.0f;
  }
  for (int s = cB + lane; s < KMAX; s += 64) {
    oiB[s] = -1.0f;
    odB[s] = 0.0f;
  }
  if (lane == 0) {
    counts[qA] = cA;
    counts[qB] = cB;
  }
}

// Single-block exclusive prefix sum of 8192 counts -> row_splits[8193] (float).
__global__ __launch_bounds__(1024) void frs_scan_kernel(
    const int* __restrict__ counts, float* __restrict__ row_splits) {
  const int t = threadIdx.x;
  const int base = t * 8;
  int c[8];
  int s = 0;
#pragma unroll
  for (int i = 0; i < 8; i++) {
    c[i] = counts[base + i];
    s += c[i];
  }
  const int lane = t & 63;
  const int wid = t >> 6;
  int incl = s;
#pragma unroll
  for (int off = 1; off < 64; off <<= 1) {
    const int v = __shfl_up(incl, off, 64);
    if (lane >= off) incl += v;
  }
  __shared__ int wpart[16];
  if (lane == 63) wpart[wid] = incl;
  __syncthreads();
  if (t == 0) {
    int run = 0;
    for (int i = 0; i < 16; i++) {
      const int v = wpart[i];
      wpart[i] = run;
      run += v;
    }
  }
  __syncthreads();
  const int excl = wpart[wid] + (incl - s);
  int run = excl;
#pragma unroll
  for (int i = 0; i < 8; i++) {
    row_splits[base + i] = (float)run;
    run += c[i];
  }
  if (t == 1023) row_splits[NQRY] = (float)run;
}

extern "C" void kernel_launch(void* const* d_in, const int* in_sizes, int n_in,
                              void* d_out, int out_size, void* d_ws, size_t ws_size,
                              hipStream_t stream) {
  const float* pts = (const float*)d_in[0];  // [N,3]
  const float* qrs = (const float*)d_in[1];  // [Q,3]
  const float* rad = (const float*)d_in[2];  // scalar

  float* out = (float*)d_out;
  float* out_idx = out;                           // [Q,K]
  float* row_splits = out + (size_t)NQRY * KMAX;  // [Q+1]
  float* out_dist = row_splits + (NQRY + 1);      // [Q,K]

  int* counts = (int*)d_ws;  // 8192 ints

  frs_v3<<<NQRY / 16, 512, 0, stream>>>(pts, qrs, rad, out_idx, out_dist,
                                        counts);
  frs_scan_kernel<<<1, 1024, 0, stream>>>(counts, row_splits);
}

// Round 14
// 89.533 us; speedup vs baseline: 1.7838x; 1.0237x over previous
//
// Round 14: issue-slot micro-bundle on the proven brute pattern. r13 showed
// per-iter cost is per-query (~43 issue slots); v4 cuts hit-path + epilogue
// slots: mbcnt for compaction offset, hits staged to LDS as float2 via one
// ds_write_b64 (no global addr math in loop), positional end-copy with
// select-padding. d2 chain / ballot order / counts / scan bit-identical.
#include <hip/hip_runtime.h>
#include <hip/hip_bf16.h>

#define NPTS 8192
#define NQRY 8192
#define KMAX 128
#define TILE 2048

// ws: counts[8192] int at offset 0 (proven writable rounds 1/8/11/12/13)

__global__ __launch_bounds__(512) void frs_v4(
    const float* __restrict__ pts, const float* __restrict__ qrs,
    const float* __restrict__ rad, float* __restrict__ out_idx,
    float* __restrict__ out_dist, int* __restrict__ counts) {
  __shared__ float4 sp[TILE];         // 32 KB: x, y, z, |p|^2
  __shared__ float2 hits[8][KMAX];    // 8 KB: {float(idx), d2} per query

  const int tid = threadIdx.x;
  const int lane = tid & 63;
  const int wid = tid >> 6;  // 0..7
  const int q = blockIdx.x * 8 + wid;

  const float qx = qrs[q * 3 + 0];
  const float qy = qrs[q * 3 + 1];
  const float qz = qrs[q * 3 + 2];
  const float r = rad[0];
  const float r2 = __fmul_rn(r, r);
  // qq = (qx*qx + qy*qy) + qz*qz — np association, no FMA contraction
  const float qq = __fadd_rn(
      __fadd_rn(__fmul_rn(qx, qx), __fmul_rn(qy, qy)), __fmul_rn(qz, qz));

  int cnt = 0;

  for (int t0 = 0; t0 < NPTS; t0 += TILE) {
    __syncthreads();  // previous tile fully consumed
    for (int p = tid; p < TILE; p += 512) {
      const int pi = t0 + p;
      const float x = pts[pi * 3 + 0];
      const float y = pts[pi * 3 + 1];
      const float z = pts[pi * 3 + 2];
      const float pp = __fadd_rn(
          __fadd_rn(__fmul_rn(x, x), __fmul_rn(y, y)), __fmul_rn(z, z));
      sp[p] = make_float4(x, y, z, pp);
    }
    __syncthreads();

#pragma unroll 4
    for (int j = lane; j < TILE; j += 64) {
      const float4 p = sp[j];
      const float dot = __fadd_rn(
          __fadd_rn(__fmul_rn(qx, p.x), __fmul_rn(qy, p.y)),
          __fmul_rn(qz, p.z));
      float d2 = __fsub_rn(__fadd_rn(qq, p.w), __fmul_rn(2.0f, dot));
      d2 = fmaxf(d2, 0.0f);
      const bool hit = d2 <= r2;
      const unsigned long long m = __ballot(hit);
      if (m) {  // skip compaction when whole wave missed (~75% of iters)
        if (hit) {
          // lanes-below-me set-bit count of m (replaces 64-bit mask+popc)
          const int off = __builtin_amdgcn_mbcnt_hi(
              (unsigned)(m >> 32),
              __builtin_amdgcn_mbcnt_lo((unsigned)m, 0u));
          const int pos = cnt + off;
          if (pos < KMAX) {
            hits[wid][pos] = make_float2((float)(t0 + j), d2);  // ds_write_b64
          }
        }
        cnt += __popcll(m);
      }
    }
  }

  // positional end-copy (NOT a reorder): slot s <- hits[wid][s], pad >= cnt.
  const int cc = cnt < KMAX ? cnt : KMAX;
  float* const oi = out_idx + (size_t)q * KMAX;
  float* const od = out_dist + (size_t)q * KMAX;
  const float2 h0 = hits[wid][lane];
  const float2 h1 = hits[wid][lane + 64];
  const bool a0 = lane < cc;
  const bool a1 = lane + 64 < cc;
  oi[lane] = a0 ? h0.x : -1.0f;
  od[lane] = a0 ? h0.y : 0.0f;
  oi[lane + 64] = a1 ? h1.x : -1.0f;
  od[lane + 64] = a1 ? h1.y : 0.0f;
  if (lane == 0) counts[q] = cnt;
}

// Single-block exclusive prefix sum of 8192 counts -> row_splits[8193] (float).
__global__ __launch_bounds__(1024) void frs_scan_kernel(
    const int* __restrict__ counts, float* __restrict__ row_splits) {
  const int t = threadIdx.x;
  const int base = t * 8;
  int c[8];
  int s = 0;
#pragma unroll
  for (int i = 0; i < 8; i++) {
    c[i] = counts[base + i];
    s += c[i];
  }
  const int lane = t & 63;
  const int wid = t >> 6;
  int incl = s;
#pragma unroll
  for (int off = 1; off < 64; off <<= 1) {
    const int v = __shfl_up(incl, off, 64);
    if (lane >= off) incl += v;
  }
  __shared__ int wpart[16];
  if (lane == 63) wpart[wid] = incl;
  __syncthreads();
  if (t == 0) {
    int run = 0;
    for (int i = 0; i < 16; i++) {
      const int v = wpart[i];
      wpart[i] = run;
      run += v;
    }
  }
  __syncthreads();
  const int excl = wpart[wid] + (incl - s);
  int run = excl;
#pragma unroll
  for (int i = 0; i < 8; i++) {
    row_splits[base + i] = (float)run;
    run += c[i];
  }
  if (t == 1023) row_splits[NQRY] = (float)run;
}

extern "C" void kernel_launch(void* const* d_in, const int* in_sizes, int n_in,
                              void* d_out, int out_size, void* d_ws, size_t ws_size,
                              hipStream_t stream) {
  const float* pts = (const float*)d_in[0];  // [N,3]
  const float* qrs = (const float*)d_in[1];  // [Q,3]
  const float* rad = (const float*)d_in[2];  // scalar

  float* out = (float*)d_out;
  float* out_idx = out;                           // [Q,K]
  float* row_splits = out + (size_t)NQRY * KMAX;  // [Q+1]
  float* out_dist = row_splits + (NQRY + 1);      // [Q,K]

  int* counts = (int*)d_ws;  // 8192 ints

  frs_v4<<<NQRY / 8, 512, 0, stream>>>(pts, qrs, rad, out_idx, out_dist,
                                       counts);
  frs_scan_kernel<<<1, 1024, 0, stream>>>(counts, row_splits);
}